// Round 1
// baseline (531.753 us; speedup 1.0000x reference)
//
#include <hip/hip_runtime.h>

constexpr int IN_F = 128;
constexpr int HID  = 64;
constexpr int OUTF = 40;

// ---------------- degrees ----------------
__global__ void deg_kernel(const int* __restrict__ src, const int* __restrict__ dst,
                           float* __restrict__ deg_out, float* __restrict__ deg_in, int E) {
    int stride = gridDim.x * blockDim.x;
    for (int i = blockIdx.x * blockDim.x + threadIdx.x; i < E; i += stride) {
        atomicAdd(&deg_out[src[i]], 1.0f);
        atomicAdd(&deg_in[dst[i]], 1.0f);
    }
}

// deg -> rsqrt(max(deg,1)), applied to the contiguous [deg_out | deg_in] block
__global__ void norm_kernel(float* __restrict__ deg, int n2) {
    int stride = gridDim.x * blockDim.x;
    for (int i = blockIdx.x * blockDim.x + threadIdx.x; i < n2; i += stride) {
        deg[i] = rsqrtf(fmaxf(deg[i], 1.0f));
    }
}

// ---------------- layer 1: H1 = (X * norm_out) @ W1 ----------------
// one wave per node; lane = output column (HID=64); X row as float2/lane + shfl
__global__ __launch_bounds__(256) void layer1_kernel(const float* __restrict__ X,
        const float* __restrict__ W1, const float* __restrict__ norm_out,
        float* __restrict__ H1, int N) {
    __shared__ float w1s[IN_F * HID];          // 32 KB
    for (int i = threadIdx.x; i < IN_F * HID; i += 256) w1s[i] = W1[i];
    __syncthreads();
    const int lane = threadIdx.x & 63;
    const int wave = threadIdx.x >> 6;
    const int step = gridDim.x * 4;
    for (int node = blockIdx.x * 4 + wave; node < N; node += step) {
        float2 v = reinterpret_cast<const float2*>(X + (size_t)node * IN_F)[lane];
        float acc = 0.f;
        #pragma unroll 16
        for (int j = 0; j < 64; ++j) {
            float xa = __shfl(v.x, j);
            float xb = __shfl(v.y, j);
            acc += xa * w1s[(2 * j) * HID + lane] + xb * w1s[(2 * j + 1) * HID + lane];
        }
        H1[(size_t)node * HID + lane] = acc * norm_out[node];
    }
}

// ---------------- scatter-aggregate layer 1 (64 feats) ----------------
__global__ void scatter1_kernel(const float* __restrict__ H1, const int* __restrict__ src,
        const int* __restrict__ dst, float* __restrict__ agg1, int E) {
    const int lane = threadIdx.x & 63;
    const int gwave = (blockIdx.x * blockDim.x + threadIdx.x) >> 6;
    const int nwaves = (gridDim.x * blockDim.x) >> 6;
    for (int e = gwave; e < E; e += nwaves) {
        int s = src[e];
        int d = dst[e];
        float val = H1[(size_t)s * HID + lane];
        atomicAdd(&agg1[(size_t)d * HID + lane], val);
    }
}

// ---------------- layer 2 fused: H2 = (relu(agg1*ni+b1)*no) @ W2 ----------------
__global__ __launch_bounds__(256) void layer2_kernel(const float* __restrict__ agg1,
        const float* __restrict__ W2, const float* __restrict__ b1,
        const float* __restrict__ norm_out, const float* __restrict__ norm_in,
        float* __restrict__ H2, int N) {
    __shared__ float w2s[HID * OUTF];          // 10.2 KB
    __shared__ float b1s[HID];
    for (int i = threadIdx.x; i < HID * OUTF; i += 256) w2s[i] = W2[i];
    if (threadIdx.x < HID) b1s[threadIdx.x] = b1[threadIdx.x];
    __syncthreads();
    const int lane = threadIdx.x & 63;
    const int wave = threadIdx.x >> 6;
    const int step = gridDim.x * 4;
    for (int node = blockIdx.x * 4 + wave; node < N; node += step) {
        float ni = norm_in[node], no = norm_out[node];
        float h = fmaxf(fmaf(agg1[(size_t)node * HID + lane], ni, b1s[lane]), 0.f) * no;
        float acc = 0.f;
        #pragma unroll 16
        for (int k = 0; k < HID; ++k) {
            float hk = __shfl(h, k);           // all lanes participate
            if (lane < OUTF) acc += hk * w2s[k * OUTF + lane];
        }
        if (lane < OUTF) H2[(size_t)node * OUTF + lane] = acc;
    }
}

// ---------------- scatter-aggregate layer 2 (40 feats, packed) ----------------
__global__ void scatter2_kernel(const float* __restrict__ H2, const int* __restrict__ src,
        const int* __restrict__ dst, float* __restrict__ out, int E) {
    const int total = E * OUTF;                // 24M < 2^31
    int stride = gridDim.x * blockDim.x;
    for (int i = blockIdx.x * blockDim.x + threadIdx.x; i < total; i += stride) {
        int e = i / OUTF;                      // magic-mul div
        int f = i - e * OUTF;
        int s = src[e];
        int d = dst[e];
        atomicAdd(&out[(size_t)d * OUTF + f], H2[(size_t)s * OUTF + f]);
    }
}

// ---------------- final: out = out * norm_in + b2 ----------------
__global__ void final_kernel(float* __restrict__ out, const float* __restrict__ norm_in,
        const float* __restrict__ b2, int N) {
    const int total = N * OUTF;
    int stride = gridDim.x * blockDim.x;
    for (int i = blockIdx.x * blockDim.x + threadIdx.x; i < total; i += stride) {
        int v = i / OUTF;
        int f = i - v * OUTF;
        out[i] = fmaf(out[i], norm_in[v], b2[f]);
    }
}

extern "C" void kernel_launch(void* const* d_in, const int* in_sizes, int n_in,
                              void* d_out, int out_size, void* d_ws, size_t ws_size,
                              hipStream_t stream) {
    const float* X   = (const float*)d_in[0];
    const int*   src = (const int*)d_in[1];
    const int*   dst = (const int*)d_in[2];
    const float* W1  = (const float*)d_in[3];
    const float* b1  = (const float*)d_in[4];
    const float* W2  = (const float*)d_in[5];
    const float* b2  = (const float*)d_in[6];
    float* out = (float*)d_out;
    const int N = in_sizes[0] / IN_F;
    const int E = in_sizes[1];

    float* deg_out = (float*)d_ws;                 // N
    float* deg_in  = deg_out + N;                  // N
    float* H1      = deg_in + N;                   // N*HID
    float* agg1    = H1 + (size_t)N * HID;         // N*HID
    float* H2      = agg1 + (size_t)N * HID;       // N*OUTF

    hipMemsetAsync(deg_out, 0, sizeof(float) * 2 * (size_t)N, stream);
    hipMemsetAsync(agg1,    0, sizeof(float) * (size_t)N * HID, stream);
    hipMemsetAsync(d_out,   0, sizeof(float) * (size_t)N * OUTF, stream);

    int degBlocks = (E + 255) / 256; if (degBlocks > 2048) degBlocks = 2048;
    deg_kernel<<<degBlocks, 256, 0, stream>>>(src, dst, deg_out, deg_in, E);
    norm_kernel<<<(2 * N + 255) / 256, 256, 0, stream>>>(deg_out, 2 * N);
    layer1_kernel<<<(N + 3) / 4, 256, 0, stream>>>(X, W1, deg_out, H1, N);
    scatter1_kernel<<<2048, 256, 0, stream>>>(H1, src, dst, agg1, E);
    layer2_kernel<<<(N + 3) / 4, 256, 0, stream>>>(agg1, W2, b1, deg_out, deg_in, H2, N);
    scatter2_kernel<<<2048, 256, 0, stream>>>(H2, src, dst, out, E);
    final_kernel<<<2048, 256, 0, stream>>>(out, deg_in, b2, N);
}

// Round 2
// 435.440 us; speedup vs baseline: 1.2212x; 1.2212x over previous
//
#include <hip/hip_runtime.h>

constexpr int IN_F = 128;
constexpr int HID  = 64;
constexpr int OUTF = 40;
constexpr int SCAN_CHUNK = 1024;   // elements per scan block (256 thr x 4)

// ---------------- degree counting (int atomics) ----------------
__global__ void deg_kernel(const int* __restrict__ src, const int* __restrict__ dst,
                           int* __restrict__ degi_out, int* __restrict__ degi_in, int E) {
    int stride = gridDim.x * blockDim.x;
    for (int i = blockIdx.x * blockDim.x + threadIdx.x; i < E; i += stride) {
        atomicAdd(&degi_out[src[i]], 1);
        atomicAdd(&degi_in[dst[i]], 1);
    }
}

// ---------------- norms from counts ----------------
__global__ void norm_kernel(const int* __restrict__ degi_out, const int* __restrict__ degi_in,
                            float* __restrict__ norm_out, float* __restrict__ norm_in, int N) {
    int stride = gridDim.x * blockDim.x;
    for (int i = blockIdx.x * blockDim.x + threadIdx.x; i < N; i += stride) {
        norm_out[i] = rsqrtf(fmaxf((float)degi_out[i], 1.0f));
        norm_in[i]  = rsqrtf(fmaxf((float)degi_in[i], 1.0f));
    }
}

// ---------------- exclusive scan of in-degrees (3 kernels) ----------------
__global__ void scan_partial_kernel(const int* __restrict__ degi, int* __restrict__ off,
                                    int* __restrict__ partials, int N) {
    __shared__ int lds[256];
    const int t = threadIdx.x;
    const int i0 = blockIdx.x * SCAN_CHUNK + t * 4;
    int v[4];
    #pragma unroll
    for (int j = 0; j < 4; ++j) v[j] = (i0 + j < N) ? degi[i0 + j] : 0;
    int s = v[0] + v[1] + v[2] + v[3];
    lds[t] = s;
    __syncthreads();
    // Hillis-Steele inclusive scan over 256 thread sums
    for (int d = 1; d < 256; d <<= 1) {
        int x = (t >= d) ? lds[t - d] : 0;
        __syncthreads();
        lds[t] += x;
        __syncthreads();
    }
    int run = lds[t] - s;                       // exclusive prefix for this thread
    if (t == 255) partials[blockIdx.x] = lds[255];
    #pragma unroll
    for (int j = 0; j < 4; ++j) {
        if (i0 + j < N) off[i0 + j] = run;
        run += v[j];
    }
}

__global__ void scan_partials_kernel(int* __restrict__ partials, int nb) {
    if (blockIdx.x == 0 && threadIdx.x == 0) {
        int run = 0;
        for (int i = 0; i < nb; ++i) { int t = partials[i]; partials[i] = run; run += t; }
    }
}

__global__ void scan_add_kernel(int* __restrict__ off, const int* __restrict__ partials,
                                int N, int E) {
    int i = blockIdx.x * blockDim.x + threadIdx.x;
    if (i < N) off[i] += partials[i / SCAN_CHUNK];
    if (i == 0) off[N] = E;
}

// ---------------- CSR fill (counting-sort scatter of edge sources) ----------------
__global__ void fill_csr_kernel(const int* __restrict__ src, const int* __restrict__ dst,
                                const int* __restrict__ off, int* __restrict__ cursor,
                                int* __restrict__ csr_src, int E) {
    int stride = gridDim.x * blockDim.x;
    for (int e = blockIdx.x * blockDim.x + threadIdx.x; e < E; e += stride) {
        int d = dst[e];
        int pos = off[d] + atomicAdd(&cursor[d], 1);
        csr_src[pos] = src[e];
    }
}

// ---------------- layer 1: H1 = (X * norm_out) @ W1 ----------------
__global__ __launch_bounds__(256) void layer1_kernel(const float* __restrict__ X,
        const float* __restrict__ W1, const float* __restrict__ norm_out,
        float* __restrict__ H1, int N) {
    __shared__ float w1s[IN_F * HID];          // 32 KB
    for (int i = threadIdx.x; i < IN_F * HID; i += 256) w1s[i] = W1[i];
    __syncthreads();
    const int lane = threadIdx.x & 63;
    const int wave = threadIdx.x >> 6;
    const int step = gridDim.x * 4;
    for (int node = blockIdx.x * 4 + wave; node < N; node += step) {
        float2 v = reinterpret_cast<const float2*>(X + (size_t)node * IN_F)[lane];
        float acc = 0.f;
        #pragma unroll 16
        for (int j = 0; j < 64; ++j) {
            float xa = __shfl(v.x, j);
            float xb = __shfl(v.y, j);
            acc += xa * w1s[(2 * j) * HID + lane] + xb * w1s[(2 * j + 1) * HID + lane];
        }
        H1[(size_t)node * HID + lane] = acc * norm_out[node];
    }
}

// ---------------- fused: agg1 gather + relu/bias/norms + @W2 -> H2 ----------------
__global__ __launch_bounds__(256) void agg1_layer2_kernel(const float* __restrict__ H1,
        const int* __restrict__ off, const int* __restrict__ csr_src,
        const float* __restrict__ W2, const float* __restrict__ b1,
        const float* __restrict__ norm_out, const float* __restrict__ norm_in,
        float* __restrict__ H2, int N) {
    __shared__ float w2s[HID * OUTF];          // 10.2 KB
    __shared__ float b1s[HID];
    for (int i = threadIdx.x; i < HID * OUTF; i += 256) w2s[i] = W2[i];
    if (threadIdx.x < HID) b1s[threadIdx.x] = b1[threadIdx.x];
    __syncthreads();
    const int lane = threadIdx.x & 63;
    const int wave = threadIdx.x >> 6;
    const int step = gridDim.x * 4;
    for (int node = blockIdx.x * 4 + wave; node < N; node += step) {
        const int e0 = off[node], e1 = off[node + 1];
        float acc = 0.f;
        for (int e = e0; e < e1; ++e) {
            int s = csr_src[e];
            acc += H1[(size_t)s * HID + lane];
        }
        float h = fmaxf(fmaf(acc, norm_in[node], b1s[lane]), 0.f) * norm_out[node];
        float o = 0.f;
        #pragma unroll 16
        for (int k = 0; k < HID; ++k) {
            float hk = __shfl(h, k);           // all lanes participate
            if (lane < OUTF) o += hk * w2s[k * OUTF + lane];
        }
        if (lane < OUTF) H2[(size_t)node * OUTF + lane] = o;
    }
}

// ---------------- gather 2: out = segsum(H2) * norm_in + b2 ----------------
__global__ __launch_bounds__(256) void agg2_kernel(const float* __restrict__ H2,
        const int* __restrict__ off, const int* __restrict__ csr_src,
        const float* __restrict__ norm_in, const float* __restrict__ b2,
        float* __restrict__ out, int N) {
    const int lane = threadIdx.x & 63;
    const int wave = threadIdx.x >> 6;
    const int step = gridDim.x * 4;
    for (int node = blockIdx.x * 4 + wave; node < N; node += step) {
        const int e0 = off[node], e1 = off[node + 1];
        if (lane < OUTF) {
            float acc = 0.f;
            for (int e = e0; e < e1; ++e) {
                int s = csr_src[e];
                acc += H2[(size_t)s * OUTF + lane];
            }
            out[(size_t)node * OUTF + lane] = fmaf(acc, norm_in[node], b2[lane]);
        }
    }
}

extern "C" void kernel_launch(void* const* d_in, const int* in_sizes, int n_in,
                              void* d_out, int out_size, void* d_ws, size_t ws_size,
                              hipStream_t stream) {
    const float* X   = (const float*)d_in[0];
    const int*   src = (const int*)d_in[1];
    const int*   dst = (const int*)d_in[2];
    const float* W1  = (const float*)d_in[3];
    const float* b1  = (const float*)d_in[4];
    const float* W2  = (const float*)d_in[5];
    const float* b2  = (const float*)d_in[6];
    float* out = (float*)d_out;
    const int N = in_sizes[0] / IN_F;
    const int E = in_sizes[1];

    // workspace layout
    int*   degi_out = (int*)d_ws;                    // N
    int*   degi_in  = degi_out + N;                  // N
    int*   off      = degi_in + N;                   // N+1
    int*   cursor   = off + N + 1;                   // N
    int*   partials = cursor + N;                    // 256
    int*   csr_src  = partials + 256;                // E
    float* norm_out = (float*)(csr_src + E);         // N
    float* norm_in  = norm_out + N;                  // N
    float* H1       = norm_in + N;                   // N*HID
    float* H2       = H1 + (size_t)N * HID;          // N*OUTF

    const int nb = (N + SCAN_CHUNK - 1) / SCAN_CHUNK;   // scan blocks (<=256)

    // zero the counters (ws is poisoned 0xAA before every timed launch)
    hipMemsetAsync(degi_out, 0, sizeof(int) * 2 * (size_t)N, stream);
    hipMemsetAsync(cursor,   0, sizeof(int) * (size_t)N, stream);

    int degBlocks = (E + 255) / 256; if (degBlocks > 2048) degBlocks = 2048;
    deg_kernel<<<degBlocks, 256, 0, stream>>>(src, dst, degi_out, degi_in, E);
    norm_kernel<<<(N + 255) / 256, 256, 0, stream>>>(degi_out, degi_in, norm_out, norm_in, N);
    scan_partial_kernel<<<nb, 256, 0, stream>>>(degi_in, off, partials, N);
    scan_partials_kernel<<<1, 64, 0, stream>>>(partials, nb);
    scan_add_kernel<<<(N + 255) / 256, 256, 0, stream>>>(off, partials, N, E);
    fill_csr_kernel<<<degBlocks, 256, 0, stream>>>(src, dst, off, cursor, csr_src, E);

    layer1_kernel<<<(N + 3) / 4, 256, 0, stream>>>(X, W1, norm_out, H1, N);
    agg1_layer2_kernel<<<(N + 3) / 4, 256, 0, stream>>>(H1, off, csr_src, W2, b1,
                                                        norm_out, norm_in, H2, N);
    agg2_kernel<<<(N + 3) / 4, 256, 0, stream>>>(H2, off, csr_src, norm_in, b2, out, N);
}